// Round 12
// baseline (1103.827 us; speedup 1.0000x reference)
//
#include <hip/hip_runtime.h>
#include <math.h>
#include <stdint.h>

#define E_N 19
#define H_N 32
#define T_N 2048
#define B_N 64
#define G_N 128      // 4*H gate rows per chain
#define XCHUNK 64    // timesteps staged per LDS round
#define LOG2E 1.4426950408889634f

typedef _Float16 half2_t __attribute__((ext_vector_type(2)));

__device__ __forceinline__ float sigm_rcp(float e) {  // 1/(1+e)
    return __builtin_amdgcn_rcpf(1.0f + e);
}

// One WAVE per TWO chains (b0=2k, b1=2k+1) sharing (e,d) => SHARED weight regs
// (32 packed fp16 dwords, the proven resident set). The two chains' steps are
// interleaved so each chain's serial path (h LDS roundtrip ~300cyc, ig swizzle
// ~150, trans ~120) is hidden by the other chain's independent issue.
// Per-chain structure identical to R8 (verified): half0 lane j owns i_j,g_j
// (ig local); half1 owns f_j,o_j (c/h local after one shfl_xor(ig,32));
// h broadcast = ds_write_b16 + 4x uniform ds_read_b128.
__global__ __launch_bounds__(64)
__attribute__((amdgpu_waves_per_eu(2, 2)))
void lstm_chain_kernel(
    const float* __restrict__ x,     // [B, T, E]
    const float* __restrict__ w_ih,  // [E, 2, 4H]
    const float* __restrict__ w_hh,  // [E, 2, 4H, H]
    const float* __restrict__ b_ih,  // [E, 2, 4H]
    const float* __restrict__ b_hh,  // [E, 2, 4H]
    float* __restrict__ hT)          // [B, E, 2, H]
{
    const int lane = threadIdx.x;
    const int pid  = blockIdx.x;             // 0..1215
    const int ed   = pid % (E_N * 2);
    const int bp   = pid / (E_N * 2);        // 0..31
    const int b0   = 2 * bp;
    const int b1   = 2 * bp + 1;
    const int e    = ed >> 1;
    const int d    = ed & 1;
    const int j    = lane & 31;
    const int half = lane >> 5;

    const int r1 = j + 32 * half;        // i_j (half0) or f_j (half1) -> sigmoid
    const int r2 = j + 64 + 32 * half;   // g_j (half0, tanh) or o_j (half1, sigmoid)

    // ---- shared weights: fp32 -> packed fp16 pairs (16+16 VGPRs) ----
    const float* wr1 = w_hh + ((size_t)ed * G_N + r1) * H_N;
    const float* wr2 = w_hh + ((size_t)ed * G_N + r2) * H_N;
    uint32_t w1p[16], w2p[16];
    #pragma unroll
    for (int m = 0; m < 16; ++m) {
        float2 v1 = ((const float2*)wr1)[m];
        float2 v2 = ((const float2*)wr2)[m];
        half2_t p1 = { (_Float16)v1.x, (_Float16)v1.y };
        half2_t p2 = { (_Float16)v2.x, (_Float16)v2.y };
        w1p[m] = __builtin_bit_cast(uint32_t, p1);
        w2p[m] = __builtin_bit_cast(uint32_t, p2);
    }

    const float wih1  = w_ih[(size_t)ed * G_N + r1];
    const float wih2  = w_ih[(size_t)ed * G_N + r2];
    const float bias1 = b_ih[(size_t)ed * G_N + r1] + b_hh[(size_t)ed * G_N + r1];
    const float bias2 = b_ih[(size_t)ed * G_N + r2] + b_hh[(size_t)ed * G_N + r2];

    // act2: half0 -> tanh(g) = 2*sigm(2g)-1 ; half1 -> sigmoid(o)
    const float K2 = half ? (-LOG2E) : (-2.0f * LOG2E);
    const float A2 = half ?  1.0f :  2.0f;
    const float B2 = half ?  0.0f : -1.0f;

    // LDS: per-chain h (slots 0..31 real, 32..63 dummy) + per-chain x chunk
    __shared__ __align__(16) uint16_t hbuf[2][64];
    __shared__ float xbuf[2][XCHUNK];

    hbuf[0][lane] = 0;
    hbuf[1][lane] = 0;
    float c0 = 0.0f, h0 = 0.0f;
    float c1 = 0.0f, h1 = 0.0f;

    const float* xbase0 = x + (size_t)b0 * T_N * E_N + e;
    const float* xbase1 = x + (size_t)b1 * T_N * E_N + e;
    const int hwr = j + 32 * (1 - half);   // half1 -> real slot j; half0 -> dummy

    for (int t0 = 0; t0 < T_N; t0 += XCHUNK) {
        // PIN: keep the 32 shared weight regs live across the inner loop (no-op).
        #pragma unroll
        for (int m = 0; m < 16; ++m) {
            asm volatile("" : "+v"(w1p[m]), "+v"(w2p[m]));
        }

        // stage 64 timesteps per chain (reversed time for d==1)
        const int tt    = t0 + lane;
        const int tphys = d ? (T_N - 1 - tt) : tt;
        xbuf[0][lane] = xbase0[(size_t)tphys * E_N];
        xbuf[1][lane] = xbase1[(size_t)tphys * E_N];

        #pragma unroll 1
        for (int tl = 0; tl < XCHUNK; ++tl) {
            // ---- h broadcasts for both chains (uniform b128 reads) ----
            const uint4* hb0 = (const uint4*)hbuf[0];
            const uint4* hb1 = (const uint4*)hbuf[1];
            const uint4 a0 = hb0[0], a1 = hb0[1], a2 = hb0[2], a3 = hb0[3];
            const uint4 d0 = hb1[0], d1 = hb1[1], d2 = hb1[2], d3 = hb1[3];
            const float sx0 = xbuf[0][tl];
            const float sx1 = xbuf[1][tl];

            uint32_t hp0[16], hp1[16];
            hp0[0]=a0.x; hp0[1]=a0.y; hp0[2]=a0.z; hp0[3]=a0.w;
            hp0[4]=a1.x; hp0[5]=a1.y; hp0[6]=a1.z; hp0[7]=a1.w;
            hp0[8]=a2.x; hp0[9]=a2.y; hp0[10]=a2.z; hp0[11]=a2.w;
            hp0[12]=a3.x; hp0[13]=a3.y; hp0[14]=a3.z; hp0[15]=a3.w;
            hp1[0]=d0.x; hp1[1]=d0.y; hp1[2]=d0.z; hp1[3]=d0.w;
            hp1[4]=d1.x; hp1[5]=d1.y; hp1[6]=d1.z; hp1[7]=d1.w;
            hp1[8]=d2.x; hp1[9]=d2.y; hp1[10]=d2.z; hp1[11]=d2.w;
            hp1[12]=d3.x; hp1[13]=d3.y; hp1[14]=d3.z; hp1[15]=d3.w;

            // ---- dots: chain0 and chain1 (independent -> scheduler interleaves) ----
            float s10 = fmaf(sx0, wih1, bias1), s11 = 0.0f;
            float s20 = fmaf(sx0, wih2, bias2), s21 = 0.0f;
            float u10 = fmaf(sx1, wih1, bias1), u11 = 0.0f;
            float u20 = fmaf(sx1, wih2, bias2), u21 = 0.0f;
            #pragma unroll
            for (int m = 0; m < 8; ++m) {
                s10 = __builtin_amdgcn_fdot2(__builtin_bit_cast(half2_t, hp0[m]),
                                             __builtin_bit_cast(half2_t, w1p[m]),   s10, false);
                s11 = __builtin_amdgcn_fdot2(__builtin_bit_cast(half2_t, hp0[m+8]),
                                             __builtin_bit_cast(half2_t, w1p[m+8]), s11, false);
                s20 = __builtin_amdgcn_fdot2(__builtin_bit_cast(half2_t, hp0[m]),
                                             __builtin_bit_cast(half2_t, w2p[m]),   s20, false);
                s21 = __builtin_amdgcn_fdot2(__builtin_bit_cast(half2_t, hp0[m+8]),
                                             __builtin_bit_cast(half2_t, w2p[m+8]), s21, false);
                u10 = __builtin_amdgcn_fdot2(__builtin_bit_cast(half2_t, hp1[m]),
                                             __builtin_bit_cast(half2_t, w1p[m]),   u10, false);
                u11 = __builtin_amdgcn_fdot2(__builtin_bit_cast(half2_t, hp1[m+8]),
                                             __builtin_bit_cast(half2_t, w1p[m+8]), u11, false);
                u20 = __builtin_amdgcn_fdot2(__builtin_bit_cast(half2_t, hp1[m]),
                                             __builtin_bit_cast(half2_t, w2p[m]),   u20, false);
                u21 = __builtin_amdgcn_fdot2(__builtin_bit_cast(half2_t, hp1[m+8]),
                                             __builtin_bit_cast(half2_t, w2p[m+8]), u21, false);
            }
            const float g1_0 = s10 + s11;
            const float g2_0 = s20 + s21;
            const float g1_1 = u10 + u11;
            const float g2_1 = u20 + u21;

            // ---- activations ----
            const float act1_0 = sigm_rcp(__builtin_amdgcn_exp2f(g1_0 * (-LOG2E)));
            const float act2_0 = fmaf(A2, sigm_rcp(__builtin_amdgcn_exp2f(g2_0 * K2)), B2);
            const float act1_1 = sigm_rcp(__builtin_amdgcn_exp2f(g1_1 * (-LOG2E)));
            const float act2_1 = fmaf(A2, sigm_rcp(__builtin_amdgcn_exp2f(g2_1 * K2)), B2);

            const float ig0  = act1_0 * act2_0;     // half0: i*g valid
            const float ig1  = act1_1 * act2_1;
            const float igx0 = __shfl_xor(ig0, 32); // half1 receives i*g
            const float igx1 = __shfl_xor(ig1, 32);

            // ---- c/h updates (valid on half1) ----
            c0 = fmaf(act1_0, c0, igx0);
            c1 = fmaf(act1_1, c1, igx1);
            const float tc0 = fmaf(2.0f, sigm_rcp(
                __builtin_amdgcn_exp2f(c0 * (-2.0f * LOG2E))), -1.0f);
            const float tc1 = fmaf(2.0f, sigm_rcp(
                __builtin_amdgcn_exp2f(c1 * (-2.0f * LOG2E))), -1.0f);
            h0 = act2_0 * tc0;
            h1 = act2_1 * tc1;

            // ---- publish h (half1 -> real slot; half0 -> dummy) ----
            hbuf[0][hwr] = __builtin_bit_cast(uint16_t, (_Float16)h0);
            hbuf[1][hwr] = __builtin_bit_cast(uint16_t, (_Float16)h1);
        }
    }

    if (half) {
        hT[((size_t)(b0 * E_N + e) * 2 + d) * H_N + j] = h0;
        hT[((size_t)(b1 * E_N + e) * 2 + d) * H_N + j] = h1;
    }
}

// LayerNorm over 64 feats per (b,e), mean over e, FC -> out[b]. One wave per b.
__global__ __launch_bounds__(64) void head_kernel(
    const float* __restrict__ hT,      // [B, E, 64]
    const float* __restrict__ ln_gamma,// [E, 64]
    const float* __restrict__ ln_beta, // [E, 64]
    const float* __restrict__ fc_w,    // [64]
    const float* __restrict__ fc_b,    // [1]
    float* __restrict__ out)           // [B]
{
    const int b = blockIdx.x;
    const int f = threadIdx.x; // 0..63

    float acc = 0.0f;
    for (int e = 0; e < E_N; ++e) {
        const float v = hT[(size_t)(b * E_N + e) * 64 + f];
        float s = v, s2 = v * v;
        #pragma unroll
        for (int off = 32; off > 0; off >>= 1) {
            s  += __shfl_xor(s,  off);
            s2 += __shfl_xor(s2, off);
        }
        const float mean = s * (1.0f / 64.0f);
        const float var  = s2 * (1.0f / 64.0f) - mean * mean;
        const float inv  = rsqrtf(var + 1e-5f);
        acc += (v - mean) * inv * ln_gamma[e * 64 + f] + ln_beta[e * 64 + f];
    }
    float contrib = (acc * (1.0f / (float)E_N)) * fc_w[f];
    #pragma unroll
    for (int off = 32; off > 0; off >>= 1) contrib += __shfl_xor(contrib, off);
    if (f == 0) out[b] = contrib + fc_b[0];
}

extern "C" void kernel_launch(void* const* d_in, const int* in_sizes, int n_in,
                              void* d_out, int out_size, void* d_ws, size_t ws_size,
                              hipStream_t stream) {
    const float* x        = (const float*)d_in[0];
    const float* w_ih     = (const float*)d_in[1];
    const float* w_hh     = (const float*)d_in[2];
    const float* b_ih     = (const float*)d_in[3];
    const float* b_hh     = (const float*)d_in[4];
    const float* ln_gamma = (const float*)d_in[5];
    const float* ln_beta  = (const float*)d_in[6];
    const float* fc_w     = (const float*)d_in[7];
    const float* fc_b     = (const float*)d_in[8];
    float* out = (float*)d_out;
    float* hT  = (float*)d_ws;  // B*E*2*H floats

    lstm_chain_kernel<<<(B_N / 2) * E_N * 2, 64, 0, stream>>>(x, w_ih, w_hh, b_ih, b_hh, hT);
    head_kernel<<<B_N, 64, 0, stream>>>(hT, ln_gamma, ln_beta, fc_w, fc_b, out);
}